// Round 6
// baseline (185.934 us; speedup 1.0000x reference)
//
#include <hip/hip_runtime.h>

#define BATCH   4096
#define IN_F    1024
#define OUT_F   1024
#define KF      8
#define KD      14336          /* trimmed GEMM K-dim: 1024 * (7 sin + 7 cos) */
#define PERI    14             /* features per input i: k=1..7 sin, k=1..7 cos */

#define BM 256
#define BN 256
#define BK 64
#define KSPLIT 4
#define KCHUNK (KD/KSPLIT)     /* 3584 */
#define NT (KCHUNK/BK)         /* 56 K-tiles per block (even) */
#define C_ELEMS ((size_t)BATCH * OUT_F)

typedef short short8 __attribute__((ext_vector_type(8)));
typedef float f32x4  __attribute__((ext_vector_type(4)));

// bf16 round-to-nearest-even from f32 (bit pattern in ushort)
__device__ __forceinline__ unsigned short f2bf(float f) {
  union { float f; unsigned int u; } v; v.f = f;
  unsigned int u = v.u;
  unsigned int lsb = (u >> 16) & 1u;
  u += 0x7fffu + lsb;
  return (unsigned short)(u >> 16);
}

__device__ __forceinline__ unsigned int pack2(float lo, float hi) {
  return (unsigned int)f2bf(lo) | ((unsigned int)f2bf(hi) << 16);
}

__device__ __forceinline__ void gload_lds16(const void* g, void* l) {
  __builtin_amdgcn_global_load_lds((const __attribute__((address_space(1))) void*)g,
                                   (__attribute__((address_space(3))) void*)l,
                                   16, 0, 0);
}

// ---------------- W conversion (k=0 trimmed) + bias = sum_i b[o,i,0] ----------------
// Thread handles one (o,i) 8-tuple of a or b. W'[o][i*14 + 0..6] = bf(a[o,i,1..7]),
// W'[o][i*14 + 7..13] = bf(b[o,i,1..7]). All threads in a block share one o.
__global__ __launch_bounds__(256) void wconv_kernel(const float* __restrict__ a,
                                                    const float* __restrict__ b,
                                                    unsigned short* __restrict__ W,
                                                    float* __restrict__ bias) {
  size_t t = (size_t)blockIdx.x * 256 + threadIdx.x;
  size_t g = t * 8;                       // element index into [a|b] stream per o
  int o = (int)(g >> 14);                 // 16384 input elems per o
  int f = (int)(g & 16383);
  const bool isB = f >= 8192;
  const int fi = isB ? f - 8192 : f;
  const int i  = fi >> 3;
  const float* src = (isB ? b : a) + (size_t)o * 8192 + fi;
  float4 v0 = reinterpret_cast<const float4*>(src)[0];   // k=0..3
  float4 v1 = reinterpret_cast<const float4*>(src)[1];   // k=4..7

  unsigned short* wp = W + (size_t)o * KD + i * PERI + (isB ? 7 : 0);
  unsigned int u12 = pack2(v0.y, v0.z);   // k1,k2
  unsigned int u34 = pack2(v0.w, v1.x);   // k3,k4
  unsigned int u56 = pack2(v1.y, v1.z);   // k5,k6
  unsigned short h7 = f2bf(v1.w);         // k7
  if (!isB) {  // byte offset ≡ 0 mod 4
    *reinterpret_cast<unsigned int*>(wp + 0) = u12;
    *reinterpret_cast<unsigned int*>(wp + 2) = u34;
    *reinterpret_cast<unsigned int*>(wp + 4) = u56;
    wp[6] = h7;
  } else {     // byte offset ≡ 2 mod 4
    wp[0] = (unsigned short)(u12 & 0xffff);
    *reinterpret_cast<unsigned int*>(wp + 1) = (u12 >> 16) | (u34 << 16);
    *reinterpret_cast<unsigned int*>(wp + 3) = (u34 >> 16) | (u56 << 16);
    *reinterpret_cast<unsigned int*>(wp + 5) = (u56 >> 16) | ((unsigned int)h7 << 16);
  }

  // bias reduce: b[o,i,0] summed over the block (single o per block), one atomic
  float bsum = isB ? v0.x : 0.f;
#pragma unroll
  for (int off = 32; off > 0; off >>= 1) bsum += __shfl_down(bsum, off);
  __shared__ float red[4];
  if ((threadIdx.x & 63) == 0) red[threadIdx.x >> 6] = bsum;
  __syncthreads();
  if (threadIdx.x == 0) atomicAdd(&bias[o], red[0] + red[1] + red[2] + red[3]);
}

// ---------------- feature kernel: Xf[b][i*14+j] = sin((j+1)x) | cos((j-6)x) ----------------
__global__ __launch_bounds__(256) void feat_kernel(const float* __restrict__ x,
                                                   unsigned short* __restrict__ Xf) {
  int idx = blockIdx.x * 256 + threadIdx.x;
  int bb = idx >> 10;
  int i  = idx & 1023;
  float xv = x[idx];
  float s1, c1;
  sincosf(xv, &s1, &c1);
  float sv[KF], cv[KF];
  sv[1] = s1;  cv[1] = c1;
#pragma unroll
  for (int k = 2; k < KF; ++k) {
    sv[k] = sv[k-1]*c1 + cv[k-1]*s1;
    cv[k] = cv[k-1]*c1 - sv[k-1]*s1;
  }
  unsigned int u[7];
  u[0] = pack2(sv[1], sv[2]);
  u[1] = pack2(sv[3], sv[4]);
  u[2] = pack2(sv[5], sv[6]);
  u[3] = pack2(sv[7], cv[1]);
  u[4] = pack2(cv[2], cv[3]);
  u[5] = pack2(cv[4], cv[5]);
  u[6] = pack2(cv[6], cv[7]);
  unsigned int* dst = reinterpret_cast<unsigned int*>(Xf + (size_t)bb * KD + i * PERI);
#pragma unroll
  for (int j = 0; j < 7; ++j) dst[j] = u[j];
}

// ---------------- GEMM: 256x256 tile, 8 waves, m201-style 8-phase pipeline ----------------
// Identical structure to R5 (best known: counted vmcnt, 2 stage-loads/phase, T2 swizzle,
// 0 bank conflicts); only K constants changed (KD=14336, NT=56).
__global__ __launch_bounds__(512, 2) void gemm_kernel(const unsigned short* __restrict__ A,
                                                      const unsigned short* __restrict__ Bt,
                                                      float* __restrict__ Cout,
                                                      int use_slab) {
  __shared__ unsigned short sA[2][BM * BK];   // 32 KiB each
  __shared__ unsigned short sB[2][BN * BK];

  const int tid  = threadIdx.x;
  const int wid  = tid >> 6;
  const int lane = tid & 63;
  const int wm = wid >> 2, wn = wid & 3;

  // bijective XCD swizzle: 256 blocks % 8 XCDs == 0; 32 consecutive work items/XCD
  const int bid = blockIdx.x;
  const int s   = (bid & 7) * 32 + (bid >> 3);
  const int z   = s >> 6;          // K-split chunk 0..3 (2 XCDs per chunk)
  const int mt  = s & 15;          // m-tile fastest -> XCD shares W panels in L2
  const int nt  = (s >> 4) & 3;
  const int m0  = mt * BM;
  const int n0  = nt * BN;
  const int fbase = z * KCHUNK;

  // ---- staging addressing (pre-swizzled global source, linear LDS dest) ----
  const int srow = wid * 8 + (lane >> 3);        // row within a 64-row group
  const int gsw  = (lane & 7) ^ (lane >> 3);     // swizzled 16B granule (involution)
  const unsigned short* pA = A  + (size_t)(m0 + srow) * KD + fbase + gsw * 8;
  const unsigned short* pB = Bt + (size_t)(n0 + srow) * KD + fbase + gsw * 8;
  const int ldst = wid * 512;                    // wave-uniform LDS elem offset in group

  // ---- fragment read addressing (swizzled) ----
  const int l15 = lane & 15;
  int kfrag[2];
#pragma unroll
  for (int ks = 0; ks < 2; ++ks)
    kfrag[ks] = ((ks * 64 + (lane >> 4) * 16) ^ ((lane & 7) << 4)) >> 1;
  const int arow = wm * 128 + l15;
  const int brow = wn * 64 + l15;

  f32x4 acc[8][4] = {};
  short8 bfr[4][2];

  // One phase: reads + 2 stage loads + barrier + 16 MFMA + (vmcnt@q3) + barrier.
#define PHASE(SAC, SBC, Q, STGP, STGDST, G0, KOFF)                              \
  {                                                                             \
    short8 af[2][2];                                                            \
    _Pragma("unroll") for (int i = 0; i < 2; ++i)                               \
      _Pragma("unroll") for (int ks = 0; ks < 2; ++ks)                          \
        af[i][ks] = *reinterpret_cast<const short8*>(                           \
            (SAC) + (arow + (2*(Q)+i)*16)*64 + kfrag[ks]);                      \
    if ((Q) == 0) {                                                             \
      _Pragma("unroll") for (int nf = 0; nf < 4; ++nf)                          \
        _Pragma("unroll") for (int ks = 0; ks < 2; ++ks)                        \
          bfr[nf][ks] = *reinterpret_cast<const short8*>(                       \
              (SBC) + (brow + nf*16)*64 + kfrag[ks]);                           \
    }                                                                           \
    gload_lds16((STGP) + (size_t)((G0)    ) * 64 * KD + (KOFF),                 \
                (STGDST) + ((G0)    ) * 4096 + ldst);                           \
    gload_lds16((STGP) + (size_t)((G0) + 1) * 64 * KD + (KOFF),                 \
                (STGDST) + ((G0) + 1) * 4096 + ldst);                           \
    if ((Q) == 0) asm volatile("s_waitcnt lgkmcnt(8)" ::: "memory");            \
    asm volatile("s_barrier" ::: "memory");                                     \
    __builtin_amdgcn_s_setprio(1);                                              \
    _Pragma("unroll") for (int i = 0; i < 2; ++i)                               \
      _Pragma("unroll") for (int nf = 0; nf < 4; ++nf)                          \
        _Pragma("unroll") for (int ks = 0; ks < 2; ++ks)                        \
          acc[2*(Q)+i][nf] = __builtin_amdgcn_mfma_f32_16x16x32_bf16(           \
              af[i][ks], bfr[nf][ks], acc[2*(Q)+i][nf], 0, 0, 0);               \
    __builtin_amdgcn_s_setprio(0);                                              \
    if ((Q) == 3) asm volatile("s_waitcnt vmcnt(4)" ::: "memory");              \
    asm volatile("s_barrier" ::: "memory");                                     \
  }

  // ---- prologue: stage tile0 (A+B) -> buf0, B(tile1) -> sB[1]; retire tile0 ----
#pragma unroll
  for (int g = 0; g < 4; ++g) {
    gload_lds16(pB + (size_t)g * 64 * KD, &sB[0][g * 4096 + ldst]);
    gload_lds16(pA + (size_t)g * 64 * KD, &sA[0][g * 4096 + ldst]);
  }
#pragma unroll
  for (int g = 0; g < 4; ++g)
    gload_lds16(pB + (size_t)g * 64 * KD + BK, &sB[1][g * 4096 + ldst]);
  asm volatile("s_waitcnt vmcnt(4)" ::: "memory");   // tile0 resident; B(1) in flight
  asm volatile("s_barrier" ::: "memory");

  for (int j = 0; j < NT / 2; ++j) {
    const int kA1 = (2 * j + 1) * BK;                           // tile 2j+1 (always real)
    const int kB2 = (2 * j + 2 < NT) ? (2 * j + 2) * BK : 0;    // tile 2j+2 (dead-wrap at end)
    const int kB3 = (2 * j + 3 < NT) ? (2 * j + 3) * BK : 0;    // tile 2j+3

    // ---- tile 2j from buf0; stage A(2j+1)->sA[1], B(2j+2)->sB[0] ----
    PHASE(&sA[0][0], &sB[0][0], 0, pA, &sA[1][0], 0, kA1)
    PHASE(&sA[0][0], &sB[0][0], 1, pA, &sA[1][0], 2, kA1)
    PHASE(&sA[0][0], &sB[0][0], 2, pB, &sB[0][0], 0, kB2)
    PHASE(&sA[0][0], &sB[0][0], 3, pB, &sB[0][0], 2, kB2)
    // ---- tile 2j+1 from buf1; stage A(2j+2)->sA[0], B(2j+3)->sB[1] ----
    PHASE(&sA[1][0], &sB[1][0], 0, pA, &sA[0][0], 0, kB2)
    PHASE(&sA[1][0], &sB[1][0], 1, pA, &sA[0][0], 2, kB2)
    PHASE(&sA[1][0], &sB[1][0], 2, pB, &sB[1][0], 0, kB3)
    PHASE(&sA[1][0], &sB[1][0], 3, pB, &sB[1][0], 2, kB3)
  }
#undef PHASE

  // ---- epilogue ----
  const int crow = m0 + wm * 128 + (lane >> 4) * 4;
  const int ccol = n0 + wn * 64 + l15;
  if (use_slab) {
    float* Cz = Cout + (size_t)z * C_ELEMS;
#pragma unroll
    for (int mf = 0; mf < 8; ++mf)
#pragma unroll
      for (int nf = 0; nf < 4; ++nf)
#pragma unroll
        for (int j = 0; j < 4; ++j)
          Cz[(size_t)(crow + mf * 16 + j) * OUT_F + ccol + nf * 16] = acc[mf][nf][j];
  } else {
#pragma unroll
    for (int mf = 0; mf < 8; ++mf)
#pragma unroll
      for (int nf = 0; nf < 4; ++nf)
#pragma unroll
        for (int j = 0; j < 4; ++j)
          atomicAdd(&Cout[(size_t)(crow + mf * 16 + j) * OUT_F + ccol + nf * 16],
                    acc[mf][nf][j]);
  }
}

// ---------------- K-split slab reduce + bias: y = s0+s1+s2+s3 + bias[o] ----------------
__global__ __launch_bounds__(256) void reduce_kernel(const f32x4* __restrict__ s,
                                                     const float* __restrict__ bias,
                                                     f32x4* __restrict__ y) {
  size_t i = (size_t)blockIdx.x * 256 + threadIdx.x;
  const size_t NQ = C_ELEMS / 4;
  f32x4 v = s[i] + s[i + NQ] + s[i + 2 * NQ] + s[i + 3 * NQ];
  v += reinterpret_cast<const f32x4*>(bias)[i & 255];   // OUT_F/4 = 256 per row
  y[i] = v;
}

// ---------------- bias broadcast (atomic-fallback init): y[b][o] = bias[o] ----------------
__global__ __launch_bounds__(256) void binit_kernel(const float* __restrict__ bias,
                                                    f32x4* __restrict__ y) {
  size_t i = (size_t)blockIdx.x * 256 + threadIdx.x;
  y[i] = reinterpret_cast<const f32x4*>(bias)[i & 255];
}

// ---------------- fallback (no workspace): direct f32 evaluation ----------------
__global__ __launch_bounds__(256) void naive_kernel(const float* __restrict__ x,
                                                    const float* __restrict__ a,
                                                    const float* __restrict__ b,
                                                    float* __restrict__ y) {
  int o  = blockIdx.x * 256 + threadIdx.x;
  int bb = blockIdx.y;
  __shared__ float xs[IN_F];
  for (int i = threadIdx.x; i < IN_F; i += 256) xs[i] = x[(size_t)bb * IN_F + i];
  __syncthreads();
  float acc = 0.f;
  for (int i = 0; i < IN_F; ++i) {
    float s1, c1; sincosf(xs[i], &s1, &c1);
    float sk = 0.f, ck = 1.f;
    const float* ap = a + (size_t)o * 8192 + i * KF;
    const float* bp = b + (size_t)o * 8192 + i * KF;
#pragma unroll
    for (int k = 0; k < KF; ++k) {
      acc += sk * ap[k] + ck * bp[k];
      float sn = sk * c1 + ck * s1;
      ck = ck * c1 - sk * s1;
      sk = sn;
    }
  }
  y[(size_t)bb * OUT_F + o] = acc;
}

extern "C" void kernel_launch(void* const* d_in, const int* in_sizes, int n_in,
                              void* d_out, int out_size, void* d_ws, size_t ws_size,
                              hipStream_t stream) {
  (void)in_sizes; (void)n_in; (void)out_size;
  const float* x = (const float*)d_in[0];
  const float* a = (const float*)d_in[1];
  const float* b = (const float*)d_in[2];
  float* y = (float*)d_out;

  const size_t XF_BYTES   = (size_t)BATCH * KD * sizeof(unsigned short);   // 112 MiB
  const size_t W_BYTES    = (size_t)OUT_F * KD * sizeof(unsigned short);   // 28 MiB
  const size_t BIAS_BYTES = (size_t)OUT_F * sizeof(float);                 // 4 KiB
  const size_t SLAB_BYTES = C_ELEMS * sizeof(float) * KSPLIT;              // 64 MiB

  if (ws_size >= XF_BYTES + W_BYTES + BIAS_BYTES) {
    unsigned short* Xf = (unsigned short*)d_ws;
    unsigned short* W  = (unsigned short*)((char*)d_ws + XF_BYTES);
    float* bias        = (float*)((char*)d_ws + XF_BYTES + W_BYTES);
    float* slabs       = (float*)((char*)d_ws + XF_BYTES + W_BYTES + BIAS_BYTES);
    const bool slab = ws_size >= XF_BYTES + W_BYTES + BIAS_BYTES + SLAB_BYTES;

    hipMemsetAsync(bias, 0, BIAS_BYTES, stream);
    wconv_kernel<<<(2 * OUT_F * IN_F * KF / 8) / 256, 256, 0, stream>>>(a, b, W, bias);
    feat_kernel<<<(BATCH * IN_F) / 256, 256, 0, stream>>>(x, Xf);
    if (slab) {
      gemm_kernel<<<dim3((BATCH / BM) * (OUT_F / BN) * KSPLIT), 512, 0, stream>>>(Xf, W, slabs, 1);
      reduce_kernel<<<(int)(C_ELEMS / 4 / 256), 256, 0, stream>>>((const f32x4*)slabs, bias, (f32x4*)y);
    } else {
      binit_kernel<<<(int)(C_ELEMS / 4 / 256), 256, 0, stream>>>(bias, (f32x4*)y);
      gemm_kernel<<<dim3((BATCH / BM) * (OUT_F / BN) * KSPLIT), 512, 0, stream>>>(Xf, W, y, 0);
    }
  } else {
    naive_kernel<<<dim3(OUT_F / 256, BATCH), 256, 0, stream>>>(x, a, b, y);
  }
}

// Round 7
// 168.524 us; speedup vs baseline: 1.1033x; 1.1033x over previous
//
#include <hip/hip_runtime.h>

#define BATCH   4096
#define IN_F    1024
#define OUT_F   1024
#define KF      8
#define KD      14336          /* trimmed GEMM K-dim: (7 sin + 7 cos) * 1024, feature-major */

#define BM 256
#define BN 256
#define BK 64
#define KSPLIT 4
#define KCHUNK (KD/KSPLIT)     /* 3584 */
#define NT (KCHUNK/BK)         /* 56 K-tiles per block (even) */
#define C_ELEMS ((size_t)BATCH * OUT_F)

typedef short short8 __attribute__((ext_vector_type(8)));
typedef float f32x4  __attribute__((ext_vector_type(4)));

// bf16 round-to-nearest-even from f32 (bit pattern in ushort)
__device__ __forceinline__ unsigned short f2bf(float f) {
  union { float f; unsigned int u; } v; v.f = f;
  unsigned int u = v.u;
  unsigned int lsb = (u >> 16) & 1u;
  u += 0x7fffu + lsb;
  return (unsigned short)(u >> 16);
}

__device__ __forceinline__ void gload_lds16(const void* g, void* l) {
  __builtin_amdgcn_global_load_lds((const __attribute__((address_space(1))) void*)g,
                                   (__attribute__((address_space(3))) void*)l,
                                   16, 0, 0);
}

// ---------------- W conversion (k=0 trimmed, feature-major) + bias ----------------
// Thread per (o,i): W[o][j*1024+i] = bf(a[o,i,j+1]) for j=0..6, bf(b[o,i,j-6]) for
// j=7..13. Consecutive lanes -> consecutive ushorts: all 14 stores coalesced.
// bias[o] = sum_i b[o,i,0] in exact f32 (block covers one o; single atomic).
__global__ __launch_bounds__(256) void wconv_kernel(const float* __restrict__ a,
                                                    const float* __restrict__ b,
                                                    unsigned short* __restrict__ W,
                                                    float* __restrict__ bias) {
  int idx = blockIdx.x * 256 + threadIdx.x;   // (o,i)
  int o = idx >> 10;
  int i = idx & 1023;
  const float4* ap = reinterpret_cast<const float4*>(a + (size_t)o * 8192 + i * 8);
  const float4* bp = reinterpret_cast<const float4*>(b + (size_t)o * 8192 + i * 8);
  float4 a0 = ap[0], a1 = ap[1];
  float4 b0 = bp[0], b1 = bp[1];

  unsigned short* wp = W + (size_t)o * KD + i;
  wp[ 0 * IN_F] = f2bf(a0.y);  wp[ 1 * IN_F] = f2bf(a0.z);  wp[ 2 * IN_F] = f2bf(a0.w);
  wp[ 3 * IN_F] = f2bf(a1.x);  wp[ 4 * IN_F] = f2bf(a1.y);  wp[ 5 * IN_F] = f2bf(a1.z);
  wp[ 6 * IN_F] = f2bf(a1.w);
  wp[ 7 * IN_F] = f2bf(b0.y);  wp[ 8 * IN_F] = f2bf(b0.z);  wp[ 9 * IN_F] = f2bf(b0.w);
  wp[10 * IN_F] = f2bf(b1.x);  wp[11 * IN_F] = f2bf(b1.y);  wp[12 * IN_F] = f2bf(b1.z);
  wp[13 * IN_F] = f2bf(b1.w);

  // bias reduce: one o per block (1024 i / 256 threads = 4 blocks per o)
  float bsum = b0.x;
#pragma unroll
  for (int off = 32; off > 0; off >>= 1) bsum += __shfl_down(bsum, off);
  __shared__ float red[4];
  if ((threadIdx.x & 63) == 0) red[threadIdx.x >> 6] = bsum;
  __syncthreads();
  if (threadIdx.x == 0) atomicAdd(&bias[o], red[0] + red[1] + red[2] + red[3]);
}

// ---------------- feature kernel (feature-major): Xf[b][j*1024+i] ----------------
// j=0..6: sin((j+1)x_bi); j=7..13: cos((j-6)x_bi). 14 coalesced 2B stores.
__global__ __launch_bounds__(256) void feat_kernel(const float* __restrict__ x,
                                                   unsigned short* __restrict__ Xf) {
  int idx = blockIdx.x * 256 + threadIdx.x;
  int bb = idx >> 10;
  int i  = idx & 1023;
  float xv = x[idx];
  float s1, c1;
  sincosf(xv, &s1, &c1);
  float sv[KF], cv[KF];
  sv[1] = s1;  cv[1] = c1;
#pragma unroll
  for (int k = 2; k < KF; ++k) {
    sv[k] = sv[k-1]*c1 + cv[k-1]*s1;
    cv[k] = cv[k-1]*c1 - sv[k-1]*s1;
  }
  unsigned short* dst = Xf + (size_t)bb * KD + i;
#pragma unroll
  for (int j = 0; j < 7; ++j) dst[j * IN_F]       = f2bf(sv[j + 1]);
#pragma unroll
  for (int j = 0; j < 7; ++j) dst[(7 + j) * IN_F] = f2bf(cv[j + 1]);
}

// ---------------- GEMM: 256x256 tile, 8 waves, 8-phase pipeline (R5/R6 structure) ----------------
// Counted vmcnt (never 0), 2 stage-loads/phase, T2 swizzle via pre-swizzled source,
// 0 bank conflicts (verified R2-R6). KD=14336, NT=56. Byte-identical to R6.
__global__ __launch_bounds__(512, 2) void gemm_kernel(const unsigned short* __restrict__ A,
                                                      const unsigned short* __restrict__ Bt,
                                                      float* __restrict__ Cout,
                                                      int use_slab) {
  __shared__ unsigned short sA[2][BM * BK];   // 32 KiB each
  __shared__ unsigned short sB[2][BN * BK];

  const int tid  = threadIdx.x;
  const int wid  = tid >> 6;
  const int lane = tid & 63;
  const int wm = wid >> 2, wn = wid & 3;

  // bijective XCD swizzle: 256 blocks % 8 XCDs == 0; 32 consecutive work items/XCD
  const int bid = blockIdx.x;
  const int s   = (bid & 7) * 32 + (bid >> 3);
  const int z   = s >> 6;          // K-split chunk 0..3 (2 XCDs per chunk)
  const int mt  = s & 15;          // m-tile fastest -> XCD shares W panels in L2
  const int nt  = (s >> 4) & 3;
  const int m0  = mt * BM;
  const int n0  = nt * BN;
  const int fbase = z * KCHUNK;

  // ---- staging addressing (pre-swizzled global source, linear LDS dest) ----
  const int srow = wid * 8 + (lane >> 3);        // row within a 64-row group
  const int gsw  = (lane & 7) ^ (lane >> 3);     // swizzled 16B granule (involution)
  const unsigned short* pA = A  + (size_t)(m0 + srow) * KD + fbase + gsw * 8;
  const unsigned short* pB = Bt + (size_t)(n0 + srow) * KD + fbase + gsw * 8;
  const int ldst = wid * 512;                    // wave-uniform LDS elem offset in group

  // ---- fragment read addressing (swizzled) ----
  const int l15 = lane & 15;
  int kfrag[2];
#pragma unroll
  for (int ks = 0; ks < 2; ++ks)
    kfrag[ks] = ((ks * 64 + (lane >> 4) * 16) ^ ((lane & 7) << 4)) >> 1;
  const int arow = wm * 128 + l15;
  const int brow = wn * 64 + l15;

  f32x4 acc[8][4] = {};
  short8 bfr[4][2];

  // One phase: reads + 2 stage loads + barrier + 16 MFMA + (vmcnt@q3) + barrier.
#define PHASE(SAC, SBC, Q, STGP, STGDST, G0, KOFF)                              \
  {                                                                             \
    short8 af[2][2];                                                            \
    _Pragma("unroll") for (int i = 0; i < 2; ++i)                               \
      _Pragma("unroll") for (int ks = 0; ks < 2; ++ks)                          \
        af[i][ks] = *reinterpret_cast<const short8*>(                           \
            (SAC) + (arow + (2*(Q)+i)*16)*64 + kfrag[ks]);                      \
    if ((Q) == 0) {                                                             \
      _Pragma("unroll") for (int nf = 0; nf < 4; ++nf)                          \
        _Pragma("unroll") for (int ks = 0; ks < 2; ++ks)                        \
          bfr[nf][ks] = *reinterpret_cast<const short8*>(                       \
              (SBC) + (brow + nf*16)*64 + kfrag[ks]);                           \
    }                                                                           \
    gload_lds16((STGP) + (size_t)((G0)    ) * 64 * KD + (KOFF),                 \
                (STGDST) + ((G0)    ) * 4096 + ldst);                           \
    gload_lds16((STGP) + (size_t)((G0) + 1) * 64 * KD + (KOFF),                 \
                (STGDST) + ((G0) + 1) * 4096 + ldst);                           \
    if ((Q) == 0) asm volatile("s_waitcnt lgkmcnt(8)" ::: "memory");            \
    asm volatile("s_barrier" ::: "memory");                                     \
    __builtin_amdgcn_s_setprio(1);                                              \
    _Pragma("unroll") for (int i = 0; i < 2; ++i)                               \
      _Pragma("unroll") for (int nf = 0; nf < 4; ++nf)                          \
        _Pragma("unroll") for (int ks = 0; ks < 2; ++ks)                        \
          acc[2*(Q)+i][nf] = __builtin_amdgcn_mfma_f32_16x16x32_bf16(           \
              af[i][ks], bfr[nf][ks], acc[2*(Q)+i][nf], 0, 0, 0);               \
    __builtin_amdgcn_s_setprio(0);                                              \
    if ((Q) == 3) asm volatile("s_waitcnt vmcnt(4)" ::: "memory");              \
    asm volatile("s_barrier" ::: "memory");                                     \
  }

  // ---- prologue: stage tile0 (A+B) -> buf0, B(tile1) -> sB[1]; retire tile0 ----
#pragma unroll
  for (int g = 0; g < 4; ++g) {
    gload_lds16(pB + (size_t)g * 64 * KD, &sB[0][g * 4096 + ldst]);
    gload_lds16(pA + (size_t)g * 64 * KD, &sA[0][g * 4096 + ldst]);
  }
#pragma unroll
  for (int g = 0; g < 4; ++g)
    gload_lds16(pB + (size_t)g * 64 * KD + BK, &sB[1][g * 4096 + ldst]);
  asm volatile("s_waitcnt vmcnt(4)" ::: "memory");   // tile0 resident; B(1) in flight
  asm volatile("s_barrier" ::: "memory");

  for (int j = 0; j < NT / 2; ++j) {
    const int kA1 = (2 * j + 1) * BK;                           // tile 2j+1 (always real)
    const int kB2 = (2 * j + 2 < NT) ? (2 * j + 2) * BK : 0;    // tile 2j+2 (dead-wrap at end)
    const int kB3 = (2 * j + 3 < NT) ? (2 * j + 3) * BK : 0;    // tile 2j+3

    // ---- tile 2j from buf0; stage A(2j+1)->sA[1], B(2j+2)->sB[0] ----
    PHASE(&sA[0][0], &sB[0][0], 0, pA, &sA[1][0], 0, kA1)
    PHASE(&sA[0][0], &sB[0][0], 1, pA, &sA[1][0], 2, kA1)
    PHASE(&sA[0][0], &sB[0][0], 2, pB, &sB[0][0], 0, kB2)
    PHASE(&sA[0][0], &sB[0][0], 3, pB, &sB[0][0], 2, kB2)
    // ---- tile 2j+1 from buf1; stage A(2j+2)->sA[0], B(2j+3)->sB[1] ----
    PHASE(&sA[1][0], &sB[1][0], 0, pA, &sA[0][0], 0, kB2)
    PHASE(&sA[1][0], &sB[1][0], 1, pA, &sA[0][0], 2, kB2)
    PHASE(&sA[1][0], &sB[1][0], 2, pB, &sB[1][0], 0, kB3)
    PHASE(&sA[1][0], &sB[1][0], 3, pB, &sB[1][0], 2, kB3)
  }
#undef PHASE

  // ---- epilogue ----
  const int crow = m0 + wm * 128 + (lane >> 4) * 4;
  const int ccol = n0 + wn * 64 + l15;
  if (use_slab) {
    float* Cz = Cout + (size_t)z * C_ELEMS;
#pragma unroll
    for (int mf = 0; mf < 8; ++mf)
#pragma unroll
      for (int nf = 0; nf < 4; ++nf)
#pragma unroll
        for (int j = 0; j < 4; ++j)
          Cz[(size_t)(crow + mf * 16 + j) * OUT_F + ccol + nf * 16] = acc[mf][nf][j];
  } else {
#pragma unroll
    for (int mf = 0; mf < 8; ++mf)
#pragma unroll
      for (int nf = 0; nf < 4; ++nf)
#pragma unroll
        for (int j = 0; j < 4; ++j)
          atomicAdd(&Cout[(size_t)(crow + mf * 16 + j) * OUT_F + ccol + nf * 16],
                    acc[mf][nf][j]);
  }
}

// ---------------- K-split slab reduce + bias: y = s0+s1+s2+s3 + bias[o] ----------------
__global__ __launch_bounds__(256) void reduce_kernel(const f32x4* __restrict__ s,
                                                     const float* __restrict__ bias,
                                                     f32x4* __restrict__ y) {
  size_t i = (size_t)blockIdx.x * 256 + threadIdx.x;
  const size_t NQ = C_ELEMS / 4;
  f32x4 v = s[i] + s[i + NQ] + s[i + 2 * NQ] + s[i + 3 * NQ];
  v += reinterpret_cast<const f32x4*>(bias)[i & 255];   // OUT_F/4 = 256 per row
  y[i] = v;
}

// ---------------- bias broadcast (atomic-fallback init): y[b][o] = bias[o] ----------------
__global__ __launch_bounds__(256) void binit_kernel(const float* __restrict__ bias,
                                                    f32x4* __restrict__ y) {
  size_t i = (size_t)blockIdx.x * 256 + threadIdx.x;
  y[i] = reinterpret_cast<const f32x4*>(bias)[i & 255];
}

// ---------------- fallback (no workspace): direct f32 evaluation ----------------
__global__ __launch_bounds__(256) void naive_kernel(const float* __restrict__ x,
                                                    const float* __restrict__ a,
                                                    const float* __restrict__ b,
                                                    float* __restrict__ y) {
  int o  = blockIdx.x * 256 + threadIdx.x;
  int bb = blockIdx.y;
  __shared__ float xs[IN_F];
  for (int i = threadIdx.x; i < IN_F; i += 256) xs[i] = x[(size_t)bb * IN_F + i];
  __syncthreads();
  float acc = 0.f;
  for (int i = 0; i < IN_F; ++i) {
    float s1, c1; sincosf(xs[i], &s1, &c1);
    float sk = 0.f, ck = 1.f;
    const float* ap = a + (size_t)o * 8192 + i * KF;
    const float* bp = b + (size_t)o * 8192 + i * KF;
#pragma unroll
    for (int k = 0; k < KF; ++k) {
      acc += sk * ap[k] + ck * bp[k];
      float sn = sk * c1 + ck * s1;
      ck = ck * c1 - sk * s1;
      sk = sn;
    }
  }
  y[(size_t)bb * OUT_F + o] = acc;
}

extern "C" void kernel_launch(void* const* d_in, const int* in_sizes, int n_in,
                              void* d_out, int out_size, void* d_ws, size_t ws_size,
                              hipStream_t stream) {
  (void)in_sizes; (void)n_in; (void)out_size;
  const float* x = (const float*)d_in[0];
  const float* a = (const float*)d_in[1];
  const float* b = (const float*)d_in[2];
  float* y = (float*)d_out;

  const size_t XF_BYTES   = (size_t)BATCH * KD * sizeof(unsigned short);   // 112 MiB
  const size_t W_BYTES    = (size_t)OUT_F * KD * sizeof(unsigned short);   // 28 MiB
  const size_t BIAS_BYTES = (size_t)OUT_F * sizeof(float);                 // 4 KiB
  const size_t SLAB_BYTES = C_ELEMS * sizeof(float) * KSPLIT;              // 64 MiB

  if (ws_size >= XF_BYTES + W_BYTES + BIAS_BYTES) {
    unsigned short* Xf = (unsigned short*)d_ws;
    unsigned short* W  = (unsigned short*)((char*)d_ws + XF_BYTES);
    float* bias        = (float*)((char*)d_ws + XF_BYTES + W_BYTES);
    float* slabs       = (float*)((char*)d_ws + XF_BYTES + W_BYTES + BIAS_BYTES);
    const bool slab = ws_size >= XF_BYTES + W_BYTES + BIAS_BYTES + SLAB_BYTES;

    hipMemsetAsync(bias, 0, BIAS_BYTES, stream);
    wconv_kernel<<<(OUT_F * IN_F) / 256, 256, 0, stream>>>(a, b, W, bias);
    feat_kernel<<<(BATCH * IN_F) / 256, 256, 0, stream>>>(x, Xf);
    if (slab) {
      gemm_kernel<<<dim3((BATCH / BM) * (OUT_F / BN) * KSPLIT), 512, 0, stream>>>(Xf, W, slabs, 1);
      reduce_kernel<<<(int)(C_ELEMS / 4 / 256), 256, 0, stream>>>((const f32x4*)slabs, bias, (f32x4*)y);
    } else {
      binit_kernel<<<(int)(C_ELEMS / 4 / 256), 256, 0, stream>>>(bias, (f32x4*)y);
      gemm_kernel<<<dim3((BATCH / BM) * (OUT_F / BN) * KSPLIT), 512, 0, stream>>>(Xf, W, y, 0);
    }
  } else {
    naive_kernel<<<dim3(OUT_F / 256, BATCH), 256, 0, stream>>>(x, a, b, y);
  }
}